// Round 1
// baseline (22835.432 us; speedup 1.0000x reference)
//
#include <hip/hip_runtime.h>
#include <hip/hip_bf16.h>
#include <hip/hip_fp16.h>
#include <stdint.h>
#include <type_traits>

// Problem constants
#define B_ 64
#define T_ 1024
#define I_ 256
#define H_ 512
#define G3_ 1536
#define O_ 256

typedef __attribute__((ext_vector_type(4))) float floatx4;
typedef __attribute__((ext_vector_type(8))) short short8;
typedef __attribute__((ext_vector_type(8))) _Float16 f16x8;
typedef __attribute__((ext_vector_type(4))) unsigned int u32x4;
typedef __attribute__((ext_vector_type(2))) unsigned int u32x2;

// Raw workgroup barrier: drains LDS only, NOT vmcnt. Keeps HBM/LLC ops
// (out stores, xg prefetch, packet stores) off the per-step critical path.
#define BARX() __asm__ volatile("s_waitcnt lgkmcnt(0)\n\ts_barrier" ::: "memory")

// A-LDS swizzle: row-major [64][512] fp16 (1024B rows) would be a full bank
// conflict on both the gather writes and the MFMA b128 reads. T2 recipe:
// XOR byte bits[6:4] with row&7, plus quarter-id bits[9:8] folded into [5:4]
// to decorrelate the gather-write quarters. Same pure function on both sides.
#define ASW(row, off) \
  (((row) << 10) + ((off) ^ (((row) & 7) << 4) ^ ((((off) >> 8) & 3) << 4)))

static __device__ __forceinline__ float sigmoid_f(float x) {
  float e = __expf(-fabsf(x));
  float a = 1.f / (1.f + e);
  return x >= 0.f ? a : 1.f - a;
}
static __device__ __forceinline__ float tanh_f(float x) {
  float e = __expf(-2.f * fabsf(x));
  float a = (1.f - e) / (1.f + e);
  return x >= 0.f ? a : -a;
}
static __device__ __forceinline__ uint32_t pack_h2(float a, float b) {
  return (uint32_t)__half_as_ushort(__float2half(a)) |
         ((uint32_t)__half_as_ushort(__float2half(b)) << 16);
}
static __device__ __forceinline__ uint32_t pack_bf2(float a, float b) {
  return (uint32_t)__builtin_bit_cast(unsigned short, __float2bfloat16(a)) |
         ((uint32_t)__builtin_bit_cast(unsigned short, __float2bfloat16(b)) << 16);
}
static __device__ __forceinline__ float lo16f(uint32_t u) {
  return __half2float(__ushort_as_half((unsigned short)(u & 0xffffu)));
}
static __device__ __forceinline__ float hi16f(uint32_t u) {
  return __half2float(__ushort_as_half((unsigned short)(u >> 16)));
}

// ---------------------------------------------------------------------------
// init: pack W_hh into fp16 MFMA B-fragments, combined biases, zero hstate.
// B-frag unit u = ((c*3 + nt)*16 + ks)*64 + lane  (one u32x4 = 8 fp16):
//   W-row = nt*512 + c*16 + (lane&15),  k = ks*32 + (lane>>4)*8 + e, e=0..7
// (Matches the lane layout of mfma_f32_16x16x32_* B operand: n = lane&15,
//  k-run = (lane>>4)*8 — identical pattern to the proven gemm_bt staging.)
// Packets need NO init: 0xAAAAAAAA poison never equals a tag (tags <= 1025).
// ---------------------------------------------------------------------------
__global__ void init_kernel(const float* __restrict__ Whh0, const float* __restrict__ Whh1,
                            const float* __restrict__ bih0, const float* __restrict__ bhh0,
                            const float* __restrict__ bih1, const float* __restrict__ bhh1,
                            u32x4* __restrict__ wq, float* __restrict__ biasv,
                            uint32_t* __restrict__ hstate) {
  int idx = blockIdx.x * 256 + threadIdx.x;
  if (idx < 196608) {
    int l = idx / 98304, r = idx % 98304;
    int lane = r & 63;
    int t1 = r >> 6;       // (c*3+nt)*16 + ks
    int ks = t1 & 15;
    int t2 = t1 >> 4;      // c*3 + nt
    int nt = t2 % 3;
    int c = t2 / 3;
    const float* W = l ? Whh1 : Whh0;
    int row = nt * 512 + c * 16 + (lane & 15);
    int k0 = ks * 32 + (lane >> 4) * 8;
    const float* wr = W + (size_t)row * 512 + k0;
    u32x4 u;
#pragma unroll
    for (int q = 0; q < 4; ++q) {
      uint32_t lo = __half_as_ushort(__float2half(wr[2 * q]));
      uint32_t hi = __half_as_ushort(__float2half(wr[2 * q + 1]));
      u[q] = lo | (hi << 16);
    }
    wq[idx] = u;
  }
  int i2 = idx - 196608;
  if (i2 >= 0 && i2 < 3072) {
    int l = i2 / 1536, n = i2 % 1536;
    const float* bi = l ? bih1 : bih0;
    const float* bh = l ? bhh1 : bhh0;
    biasv[i2] = bi[n] + (n < 1024 ? bh[n] : 0.f);
  }
  int i3 = idx - (196608 + 3072);
  if (i3 >= 0 && i3 < 32768) hstate[i3] = 0u;
}

// ---------------------------------------------------------------------------
// GEMM: C[M,N] = A[M,K] * Bw[N,K]^T + bias, bf16 MFMA 16x16x32. (unchanged)
// ---------------------------------------------------------------------------
template <typename TA, typename TC>
__global__ __launch_bounds__(256, 2) void gemm_bt(
    const TA* __restrict__ A, const float* __restrict__ Bw,
    const float* __restrict__ bias, TC* __restrict__ C,
    int K, int lda, int ldc, int tcshift, int t0, int Ttot) {
  __shared__ unsigned short As[128 * 40];
  __shared__ unsigned short Bs[128 * 40];
  const int tid = threadIdx.x;
  const int bm = blockIdx.x, bn = blockIdx.y;
  const int r = tid >> 1, hf = tid & 1;

  const int m = bm * 128 + r;
  const long arow = (long)(m >> tcshift) * Ttot + t0 + (m & ((1 << tcshift) - 1));
  const TA* ap = A + arow * (long)lda + hf * 16;
  const int n = bn * 128 + r;
  const float* bp = Bw + (long)n * K + hf * 16;

  const int wid = tid >> 6, lane = tid & 63;
  const int wm = (wid >> 1) * 64, wn = (wid & 1) * 64;
  const int m16 = lane & 15, quad = lane >> 4;

  floatx4 acc[4][4];
#pragma unroll
  for (int i = 0; i < 4; ++i)
#pragma unroll
    for (int j = 0; j < 4; ++j) acc[i][j] = 0.f;

  for (int k0 = 0; k0 < K; k0 += 32) {
    unsigned short ta[16], tb[16];
    if constexpr (std::is_same<TA, float>::value) {
      const float4* p = (const float4*)(ap + k0);
#pragma unroll
      for (int q = 0; q < 4; ++q) {
        float4 v = p[q];
        ta[q * 4 + 0] = __builtin_bit_cast(unsigned short, __float2bfloat16(v.x));
        ta[q * 4 + 1] = __builtin_bit_cast(unsigned short, __float2bfloat16(v.y));
        ta[q * 4 + 2] = __builtin_bit_cast(unsigned short, __float2bfloat16(v.z));
        ta[q * 4 + 3] = __builtin_bit_cast(unsigned short, __float2bfloat16(v.w));
      }
    } else {
      const uint4* p = (const uint4*)(ap + k0);
      *(uint4*)&ta[0] = p[0];
      *(uint4*)&ta[8] = p[1];
    }
    {
      const float4* p = (const float4*)(bp + k0);
#pragma unroll
      for (int q = 0; q < 4; ++q) {
        float4 v = p[q];
        tb[q * 4 + 0] = __builtin_bit_cast(unsigned short, __float2bfloat16(v.x));
        tb[q * 4 + 1] = __builtin_bit_cast(unsigned short, __float2bfloat16(v.y));
        tb[q * 4 + 2] = __builtin_bit_cast(unsigned short, __float2bfloat16(v.z));
        tb[q * 4 + 3] = __builtin_bit_cast(unsigned short, __float2bfloat16(v.w));
      }
    }
    *(uint4*)&As[r * 40 + hf * 16] = *(uint4*)&ta[0];
    *(uint4*)&As[r * 40 + hf * 16 + 8] = *(uint4*)&ta[8];
    *(uint4*)&Bs[r * 40 + hf * 16] = *(uint4*)&tb[0];
    *(uint4*)&Bs[r * 40 + hf * 16 + 8] = *(uint4*)&tb[8];
    __syncthreads();
    short8 af[4], bfr[4];
#pragma unroll
    for (int mt = 0; mt < 4; ++mt)
      af[mt] = *(const short8*)&As[(wm + mt * 16 + m16) * 40 + quad * 8];
#pragma unroll
    for (int nt = 0; nt < 4; ++nt)
      bfr[nt] = *(const short8*)&Bs[(wn + nt * 16 + m16) * 40 + quad * 8];
#pragma unroll
    for (int mt = 0; mt < 4; ++mt)
#pragma unroll
      for (int nt = 0; nt < 4; ++nt)
        acc[mt][nt] = __builtin_amdgcn_mfma_f32_16x16x32_bf16(af[mt], bfr[nt],
                                                              acc[mt][nt], 0, 0, 0);
    __syncthreads();
  }
#pragma unroll
  for (int mt = 0; mt < 4; ++mt)
#pragma unroll
    for (int nt = 0; nt < 4; ++nt)
#pragma unroll
      for (int rr = 0; rr < 4; ++rr) {
        int grow = bm * 128 + wm + mt * 16 + quad * 4 + rr;
        int gcol = bn * 128 + wn + nt * 16 + m16;
        float v = acc[mt][nt][rr];
        if (bias) v += bias[gcol];
        if constexpr (std::is_same<TC, float>::value)
          C[(long)grow * ldc + gcol] = v;
        else
          C[(long)grow * ldc + gcol] = __float2half(v);
      }
}

// ---------------------------------------------------------------------------
// GRU recurrence, ALL-BATCH MFMA design. 32 WGs x 256 threads.
// WG c owns h-cols [16c,16c+16) for ALL 64 batches; its 48 W_hh rows (r,z,n)
// live as MFMA B-fragments in 192 VGPRs (weights stored once chip-wide, not
// 64x-replicated like the old 256-WG fdot2 design).
// Per step:
//  1. gather full H(t): thread (b=tid>>2, p0=(tid&3)*64) pulls 64 tagged u64
//     packets {fp16x2,tag} with a 4-bank software pipeline (counted waitcnts)
//     -> XOR-swizzled A-LDS [64][512] fp16. Retry stale groups. tt==0 seeds
//     from hstate (tag-free).
//  2. BARX; waves 0,1 (m-split: batches 0-31 / 32-63): 16 k-steps x
//     {2 ds_read_b128 A-frags, 6 mfma_f32_16x16x32_f16} ; each lane's acc
//     holds ALL 3 gates of its column -> D to LDS [batch][52] f32.
//  3. BARX; all 256 threads: 4 gate-triples each (b=tid>>2, 4 cols), xg from
//     prefetched regs, publish h(t+1) as 2 tagged u64 packets, bf16 out store.
// One publish->poll L3 round trip per step (was the same, but now 32 WGs and
// MFMA compute). Packet protocol/tags/slot-parity identical to the proven
// kernel (publish-implies-consumed induction => 2-slot reuse safe).
// ---------------------------------------------------------------------------
__global__ __launch_bounds__(256, 1) void gru_rec(
    const u32x4* __restrict__ wq, const uint32_t* __restrict__ xgd,
    const float* __restrict__ bhh, uint32_t* __restrict__ hstate,
    uint32_t* __restrict__ outw, uint64_t* __restrict__ pkts,
    float* __restrict__ hid_out,
    int t0, int Tc, int outT, int outT0, int last) {
  const int tid = threadIdx.x;
  const int lane = tid & 63;
  const int wave = tid >> 6;
  const int c = blockIdx.x;        // h-col chunk 0..31
  const int bg = tid >> 2;         // batch 0..63 (gather & gates identity)
  const int qg = tid & 3;          // quarter
  const int p0 = qg * 64;          // gather pair-range [p0,p0+64)
  const int J0 = c * 16 + qg * 4;  // this thread's 4 h-columns

  __shared__ unsigned short Al[64 * 512];  // H(t) fp16, XOR-swizzled
  __shared__ float Dl[64 * 52];            // W_hh.h pre-acts [batch][48+pad]

  // ---- B-fragments: 48 x u32x4 = 192 VGPRs (only waves 0,1 load/use) ----
  u32x4 Bf[3][16];
  if (wave < 2) {
    const u32x4* wp = wq + (size_t)c * 3072 + lane;
#pragma unroll
    for (int nt = 0; nt < 3; ++nt)
#pragma unroll
      for (int ks = 0; ks < 16; ++ks) Bf[nt][ks] = wp[(nt * 16 + ks) * 64];
  }

  // ---- gates persistent state: h_old, n-bias, current-step xg ----
  float hold[4];
  floatx4 bn = *(const floatx4*)&bhh[1024 + J0];
  u32x2 nx0, nx1, nx2;
  {
    u32x2 hs = *(const u32x2*)&hstate[bg * 256 + (J0 >> 1)];
    hold[0] = lo16f(hs.x); hold[1] = hi16f(hs.x);
    hold[2] = lo16f(hs.y); hold[3] = hi16f(hs.y);
    size_t xb = (size_t)bg * Tc * 768 + (J0 >> 1);
    nx0 = *(const u32x2*)&xgd[xb];
    nx1 = *(const u32x2*)&xgd[xb + 256];
    nx2 = *(const u32x2*)&xgd[xb + 512];
  }

  for (int tt = 0; tt < Tc; ++tt) {
    const int t = t0 + tt;
    // ---------------- gather H(t) into Al ----------------
    if (tt == 0) {
      const uint32_t* hp = &hstate[bg * 256 + p0];
#pragma unroll
      for (int j = 0; j < 16; ++j) {
        u32x4 v = *(const u32x4*)&hp[j * 4];
        *(u32x4*)((char*)Al + ASW(bg, (p0 + j * 4) * 4)) = v;
      }
    } else {
      const uint64_t* pb = pkts + (((size_t)(t & 1)) * 64 + bg) * 256 + p0;
      const uint32_t tg = (uint32_t)t;
      uint64_t stg[4][8];
      uint32_t fail = 0;
      __builtin_amdgcn_s_sleep(2);  // let publish stores propagate to L3
      // 4-bank pipeline: 32 loads in flight; compiler emits counted waitcnts
#pragma unroll
      for (int g = 0; g < 4; ++g)
#pragma unroll
        for (int j = 0; j < 8; ++j)
          stg[g][j] = __hip_atomic_load(&pb[g * 8 + j], __ATOMIC_RELAXED,
                                        __HIP_MEMORY_SCOPE_AGENT);
#pragma unroll
      for (int g = 0; g < 8; ++g) {
        const int bk = g & 3;
        uint32_t bad = 0;
#pragma unroll
        for (int j = 0; j < 8; j += 2) {
          uint64_t v0 = stg[bk][j], v1 = stg[bk][j + 1];
          bad |= ((uint32_t)(v0 >> 32) ^ tg) | ((uint32_t)(v1 >> 32) ^ tg);
          u32x2 w;
          w.x = (uint32_t)v0;
          w.y = (uint32_t)v1;
          *(u32x2*)((char*)Al + ASW(bg, (p0 + g * 8 + j) * 4)) = w;
        }
        fail |= (bad ? 1u : 0u) << g;
        if (g < 4) {
#pragma unroll
          for (int j = 0; j < 8; ++j)
            stg[bk][j] = __hip_atomic_load(&pb[(g + 4) * 8 + j], __ATOMIC_RELAXED,
                                           __HIP_MEMORY_SCOPE_AGENT);
        }
      }
      // retry stale groups (stale data already in Al gets rewritten)
      while (fail) {
        __builtin_amdgcn_s_sleep(2);
        uint32_t nf = 0;
#pragma unroll
        for (int g = 0; g < 8; ++g) {
          if (fail & (1u << g)) {
            uint64_t v[8];
#pragma unroll
            for (int j = 0; j < 8; ++j)
              v[j] = __hip_atomic_load(&pb[g * 8 + j], __ATOMIC_RELAXED,
                                       __HIP_MEMORY_SCOPE_AGENT);
            uint32_t bad = 0;
#pragma unroll
            for (int j = 0; j < 8; j += 2) {
              bad |= ((uint32_t)(v[j] >> 32) ^ tg) | ((uint32_t)(v[j + 1] >> 32) ^ tg);
              u32x2 w;
              w.x = (uint32_t)v[j];
              w.y = (uint32_t)v[j + 1];
              *(u32x2*)((char*)Al + ASW(bg, (p0 + g * 8 + j) * 4)) = w;
            }
            nf |= (bad ? 1u : 0u) << g;
          }
        }
        fail = nf;
      }
    }
    // prefetch next step's xg (fire-and-forget; consumed at next gates)
    u32x2 px0, px1, px2;
    const bool havepx = (tt + 1 < Tc);
    if (havepx) {
      size_t xb = ((size_t)bg * Tc + tt + 1) * 768 + (J0 >> 1);
      px0 = *(const u32x2*)&xgd[xb];
      px1 = *(const u32x2*)&xgd[xb + 256];
      px2 = *(const u32x2*)&xgd[xb + 512];
    }
    BARX();  // A complete

    // ---------------- MFMA: D = H(t) . W_slice^T ----------------
    if (wave < 2) {
      const int r15 = lane & 15, q4 = lane >> 4;
      const int rA = wave * 32 + r15;
      const int rB = rA + 16;
      floatx4 acc[2][3];
#pragma unroll
      for (int mt = 0; mt < 2; ++mt)
#pragma unroll
        for (int nt = 0; nt < 3; ++nt)
#pragma unroll
          for (int e = 0; e < 4; ++e) acc[mt][nt][e] = 0.f;
#pragma unroll
      for (int ks = 0; ks < 16; ++ks) {
        const int off = ks * 64 + q4 * 16;
        f16x8 a0 = __builtin_bit_cast(f16x8, *(const u32x4*)((const char*)Al + ASW(rA, off)));
        f16x8 a1 = __builtin_bit_cast(f16x8, *(const u32x4*)((const char*)Al + ASW(rB, off)));
#pragma unroll
        for (int nt = 0; nt < 3; ++nt) {
          f16x8 bf = __builtin_bit_cast(f16x8, Bf[nt][ks]);
          acc[0][nt] = __builtin_amdgcn_mfma_f32_16x16x32_f16(a0, bf, acc[0][nt], 0, 0, 0);
          acc[1][nt] = __builtin_amdgcn_mfma_f32_16x16x32_f16(a1, bf, acc[1][nt], 0, 0, 0);
        }
      }
      // D: batch = wave*32 + mt*16 + q4*4 + rr ; local col = nt*16 + r15
#pragma unroll
      for (int mt = 0; mt < 2; ++mt)
#pragma unroll
        for (int nt = 0; nt < 3; ++nt)
#pragma unroll
          for (int rr = 0; rr < 4; ++rr)
            Dl[(wave * 32 + mt * 16 + q4 * 4 + rr) * 52 + nt * 16 + r15] =
                acc[mt][nt][rr];
    }
    BARX();  // D complete

    // ---------------- gates: 4 (b, J) triples per thread ----------------
    {
      floatx4 dr = *(const floatx4*)&Dl[bg * 52 + qg * 4];
      floatx4 dz = *(const floatx4*)&Dl[bg * 52 + 16 + qg * 4];
      floatx4 dn = *(const floatx4*)&Dl[bg * 52 + 32 + qg * 4];
      float xr[4] = {lo16f(nx0.x), hi16f(nx0.x), lo16f(nx0.y), hi16f(nx0.y)};
      float xz[4] = {lo16f(nx1.x), hi16f(nx1.x), lo16f(nx1.y), hi16f(nx1.y)};
      float xn[4] = {lo16f(nx2.x), hi16f(nx2.x), lo16f(nx2.y), hi16f(nx2.y)};
      float h[4];
#pragma unroll
      for (int e = 0; e < 4; ++e) {
        float r = sigmoid_f(xr[e] + dr[e]);
        float z = sigmoid_f(xz[e] + dz[e]);
        float n = tanh_f(xn[e] + r * (dn[e] + bn[e]));
        h[e] = (1.f - z) * n + z * hold[e];
        hold[e] = h[e];
      }
      uint32_t d0 = pack_h2(h[0], h[1]);
      uint32_t d1 = pack_h2(h[2], h[3]);
      const uint64_t tagw = ((uint64_t)(uint32_t)(t + 1)) << 32;
      uint64_t* pp = &pkts[(((size_t)((t + 1) & 1)) * 64 + bg) * 256 + (J0 >> 1)];
      __hip_atomic_store(pp, (uint64_t)d0 | tagw, __ATOMIC_RELAXED,
                         __HIP_MEMORY_SCOPE_AGENT);
      __hip_atomic_store(pp + 1, (uint64_t)d1 | tagw, __ATOMIC_RELAXED,
                         __HIP_MEMORY_SCOPE_AGENT);
      u32x2 ow;
      ow.x = pack_bf2(h[0], h[1]);
      ow.y = pack_bf2(h[2], h[3]);
      *(u32x2*)&outw[((size_t)bg * outT + outT0 + tt) * 256 + (J0 >> 1)] = ow;
    }
    if (havepx) { nx0 = px0; nx1 = px1; nx2 = px2; }
  }

  // carry h to next dispatch / final hidden output
  {
    u32x2 hs;
    hs.x = pack_h2(hold[0], hold[1]);
    hs.y = pack_h2(hold[2], hold[3]);
    *(u32x2*)&hstate[bg * 256 + (J0 >> 1)] = hs;
    if (last) {
      floatx4 hv;
      hv[0] = hold[0]; hv[1] = hold[1]; hv[2] = hold[2]; hv[3] = hold[3];
      *(floatx4*)&hid_out[bg * 512 + J0] = hv;
    }
  }
}

// ---------------------------------------------------------------------------
extern "C" void kernel_launch(void* const* d_in, const int* in_sizes, int n_in,
                              void* d_out, int out_size, void* d_ws, size_t ws_size,
                              hipStream_t stream) {
  const float* x = (const float*)d_in[0];
  const float* W_ih0 = (const float*)d_in[1];
  const float* W_hh0 = (const float*)d_in[2];
  const float* b_ih0 = (const float*)d_in[3];
  const float* b_hh0 = (const float*)d_in[4];
  const float* W_ih1 = (const float*)d_in[5];
  const float* W_hh1 = (const float*)d_in[6];
  const float* b_ih1 = (const float*)d_in[7];
  const float* b_hh1 = (const float*)d_in[8];
  const float* fc_w = (const float*)d_in[9];
  const float* fc_b = (const float*)d_in[10];
  float* out = (float*)d_out;

  char* p = (char*)d_ws;
  size_t off = 0;
  auto alloc = [&](size_t bytes) -> void* {
    void* r = p + off;
    off = (off + bytes + 255) & ~(size_t)255;
    return r;
  };
  u32x4* wq = (u32x4*)alloc((size_t)196608 * 16);  // 2 layers of W_hh B-frags
  float* biasv = (float*)alloc((size_t)3072 * 4);
  uint32_t* hstate = (uint32_t*)alloc((size_t)32768 * 4);
  // packets: 2 layers x 2 slots x 64 batch x 256 pairs x u64
  uint64_t* pkts = (uint64_t*)alloc((size_t)2 * 2 * 64 * 256 * 8);
  __hip_bfloat16* out1 = (__hip_bfloat16*)alloc((size_t)B_ * T_ * H_ * 2);

  int Tc = 1024;
  while (Tc > 64) {
    size_t need = (size_t)B_ * Tc * H_ * 2 + (size_t)B_ * Tc * G3_ * 2 + 1024;
    if (off + need <= ws_size) break;
    Tc >>= 1;
  }
  __hip_bfloat16* out0c = (__hip_bfloat16*)alloc((size_t)B_ * Tc * H_ * 2);
  __half* xg = (__half*)alloc((size_t)B_ * Tc * G3_ * 2);
  int tcs = __builtin_ctz(Tc);

  init_kernel<<<909, 256, 0, stream>>>(W_hh0, W_hh1, b_ih0, b_hh0, b_ih1, b_hh1,
                                       wq, biasv, hstate);

  for (int t0 = 0; t0 < 1024; t0 += Tc) {
    const int M = B_ * Tc;
    const int last = (t0 + Tc) == 1024;
    // ---- layer 0 ----
    {
      dim3 gg(M / 128, G3_ / 128);
      gemm_bt<float, __half><<<gg, 256, 0, stream>>>(x, W_ih0, biasv, xg, I_, I_,
                                                     G3_, tcs, t0, 1024);
      gru_rec<<<32, 256, 0, stream>>>(wq, (const uint32_t*)xg, b_hh0, hstate,
                                      (uint32_t*)out0c, pkts,
                                      out + 16777216, t0, Tc, Tc, 0, last);
    }
    // ---- layer 1 ----
    {
      dim3 gg(M / 128, G3_ / 128);
      gemm_bt<__hip_bfloat16, __half><<<gg, 256, 0, stream>>>(
          out0c, W_ih1, biasv + 1536, xg, H_, H_, G3_, tcs, 0, Tc);
      gru_rec<<<32, 256, 0, stream>>>(wq + 98304, (const uint32_t*)xg, b_hh1,
                                      hstate + 16384, (uint32_t*)out1,
                                      pkts + 32768,
                                      out + 16777216 + 32768, t0, Tc, 1024, t0, last);
    }
  }
  // FC: [65536,512] x fc_w[256,512]^T + fc_b -> d_out fp32
  dim3 gf(65536 / 128, O_ / 128);
  gemm_bt<__hip_bfloat16, float><<<gf, 256, 0, stream>>>(out1, fc_w, fc_b, out,
                                                         H_, H_, O_, 10, 0, 1024);
}

// Round 2
// 4414.285 us; speedup vs baseline: 5.1731x; 5.1731x over previous
//
#include <hip/hip_runtime.h>
#include <hip/hip_bf16.h>
#include <hip/hip_fp16.h>
#include <stdint.h>
#include <type_traits>

// Problem constants
#define B_ 64
#define T_ 1024
#define I_ 256
#define H_ 512
#define G3_ 1536
#define O_ 256

typedef __attribute__((ext_vector_type(4))) float floatx4;
typedef __attribute__((ext_vector_type(8))) short short8;
typedef __attribute__((ext_vector_type(2))) _Float16 half2v;

// Raw workgroup barrier: drains LDS only, NOT vmcnt. Keeps HBM/LLC ops
// (out stores, xg prefetch, packet stores) off the per-step critical path.
#define BARX() __asm__ volatile("s_waitcnt lgkmcnt(0)\n\ts_barrier" ::: "memory")

static __device__ __forceinline__ float fdot2f(uint32_t a, uint32_t b, float c) {
#if __has_builtin(__builtin_amdgcn_fdot2)
  return __builtin_amdgcn_fdot2(__builtin_bit_cast(half2v, a),
                                __builtin_bit_cast(half2v, b), c, false);
#else
  __half2 ha = __builtin_bit_cast(__half2, a);
  __half2 hb = __builtin_bit_cast(__half2, b);
  float2 fa = __half22float2(ha), fb = __half22float2(hb);
  return c + fa.x * fb.x + fa.y * fb.y;
#endif
}

static __device__ __forceinline__ float sigmoid_f(float x) {
  float e = __expf(-fabsf(x));
  float a = 1.f / (1.f + e);
  return x >= 0.f ? a : 1.f - a;
}
static __device__ __forceinline__ float tanh_f(float x) {
  float e = __expf(-2.f * fabsf(x));
  float a = (1.f - e) / (1.f + e);
  return x >= 0.f ? a : -a;
}
static __device__ __forceinline__ uint32_t pack_h2(float a, float b) {
  return (uint32_t)__half_as_ushort(__float2half(a)) |
         ((uint32_t)__half_as_ushort(__float2half(b)) << 16);
}
static __device__ __forceinline__ uint32_t pack_bf2(float a, float b) {
  return (uint32_t)__builtin_bit_cast(unsigned short, __float2bfloat16(a)) |
         ((uint32_t)__builtin_bit_cast(unsigned short, __float2bfloat16(b)) << 16);
}

// ---------------------------------------------------------------------------
// init: pack W_hh -> fp16 register layout, combined biases, zero hstate.
// wpack dword index: j + 128*g + 384*kk + 24576*s + 98304*c + 393216*l
// Packets need NO init: 0xAAAAAAAA poison never equals a tag (tags <= 1025).
// ---------------------------------------------------------------------------
__global__ void init_kernel(const float* __restrict__ Whh0, const float* __restrict__ Whh1,
                            const float* __restrict__ bih0, const float* __restrict__ bhh0,
                            const float* __restrict__ bih1, const float* __restrict__ bhh1,
                            uint32_t* __restrict__ wpack, float* __restrict__ biasv,
                            uint32_t* __restrict__ hstate) {
  int idx = blockIdx.x * 256 + threadIdx.x;
  if (idx < 786432) {
    int l = idx / 393216, rem = idx % 393216;
    int j = rem & 127;
    int g = (rem >> 7) % 3;
    int kk = (rem / 384) & 63;
    int s = (rem / 24576) & 3;
    int c = rem / 98304;
    const float* W = l ? Whh1 : Whh0;
    int row = g * 512 + c * 128 + j;
    int k = s * 128 + kk * 2;
    uint32_t lo = __half_as_ushort(__float2half(W[(size_t)row * 512 + k]));
    uint32_t hi = __half_as_ushort(__float2half(W[(size_t)row * 512 + k + 1]));
    wpack[idx] = lo | (hi << 16);
  }
  int i2 = idx - 786432;
  if (i2 >= 0 && i2 < 3072) {
    int l = i2 / 1536, n = i2 % 1536;
    const float* bi = l ? bih1 : bih0;
    const float* bh = l ? bhh1 : bhh0;
    biasv[i2] = bi[n] + (n < 1024 ? bh[n] : 0.f);
  }
  int i3 = idx - (786432 + 3072);
  if (i3 >= 0 && i3 < 32768) hstate[i3] = 0u;
}

// ---------------------------------------------------------------------------
// GEMM: C[M,N] = A[M,K] * Bw[N,K]^T + bias, bf16 MFMA 16x16x32.
// A row = (m>>tcs)*Ttot + t0 + (m & (Tc-1))  (handles chunked [B,T,*]).
// ---------------------------------------------------------------------------
template <typename TA, typename TC>
__global__ __launch_bounds__(256, 2) void gemm_bt(
    const TA* __restrict__ A, const float* __restrict__ Bw,
    const float* __restrict__ bias, TC* __restrict__ C,
    int K, int lda, int ldc, int tcshift, int t0, int Ttot) {
  __shared__ unsigned short As[128 * 40];
  __shared__ unsigned short Bs[128 * 40];
  const int tid = threadIdx.x;
  const int bm = blockIdx.x, bn = blockIdx.y;
  const int r = tid >> 1, hf = tid & 1;

  const int m = bm * 128 + r;
  const long arow = (long)(m >> tcshift) * Ttot + t0 + (m & ((1 << tcshift) - 1));
  const TA* ap = A + arow * (long)lda + hf * 16;
  const int n = bn * 128 + r;
  const float* bp = Bw + (long)n * K + hf * 16;

  const int wid = tid >> 6, lane = tid & 63;
  const int wm = (wid >> 1) * 64, wn = (wid & 1) * 64;
  const int m16 = lane & 15, quad = lane >> 4;

  floatx4 acc[4][4];
#pragma unroll
  for (int i = 0; i < 4; ++i)
#pragma unroll
    for (int j = 0; j < 4; ++j) acc[i][j] = 0.f;

  for (int k0 = 0; k0 < K; k0 += 32) {
    unsigned short ta[16], tb[16];
    if constexpr (std::is_same<TA, float>::value) {
      const float4* p = (const float4*)(ap + k0);
#pragma unroll
      for (int q = 0; q < 4; ++q) {
        float4 v = p[q];
        ta[q * 4 + 0] = __builtin_bit_cast(unsigned short, __float2bfloat16(v.x));
        ta[q * 4 + 1] = __builtin_bit_cast(unsigned short, __float2bfloat16(v.y));
        ta[q * 4 + 2] = __builtin_bit_cast(unsigned short, __float2bfloat16(v.z));
        ta[q * 4 + 3] = __builtin_bit_cast(unsigned short, __float2bfloat16(v.w));
      }
    } else {
      const uint4* p = (const uint4*)(ap + k0);
      *(uint4*)&ta[0] = p[0];
      *(uint4*)&ta[8] = p[1];
    }
    {
      const float4* p = (const float4*)(bp + k0);
#pragma unroll
      for (int q = 0; q < 4; ++q) {
        float4 v = p[q];
        tb[q * 4 + 0] = __builtin_bit_cast(unsigned short, __float2bfloat16(v.x));
        tb[q * 4 + 1] = __builtin_bit_cast(unsigned short, __float2bfloat16(v.y));
        tb[q * 4 + 2] = __builtin_bit_cast(unsigned short, __float2bfloat16(v.z));
        tb[q * 4 + 3] = __builtin_bit_cast(unsigned short, __float2bfloat16(v.w));
      }
    }
    *(uint4*)&As[r * 40 + hf * 16] = *(uint4*)&ta[0];
    *(uint4*)&As[r * 40 + hf * 16 + 8] = *(uint4*)&ta[8];
    *(uint4*)&Bs[r * 40 + hf * 16] = *(uint4*)&tb[0];
    *(uint4*)&Bs[r * 40 + hf * 16 + 8] = *(uint4*)&tb[8];
    __syncthreads();
    short8 af[4], bfr[4];
#pragma unroll
    for (int mt = 0; mt < 4; ++mt)
      af[mt] = *(const short8*)&As[(wm + mt * 16 + m16) * 40 + quad * 8];
#pragma unroll
    for (int nt = 0; nt < 4; ++nt)
      bfr[nt] = *(const short8*)&Bs[(wn + nt * 16 + m16) * 40 + quad * 8];
#pragma unroll
    for (int mt = 0; mt < 4; ++mt)
#pragma unroll
      for (int nt = 0; nt < 4; ++nt)
        acc[mt][nt] = __builtin_amdgcn_mfma_f32_16x16x32_bf16(af[mt], bfr[nt],
                                                              acc[mt][nt], 0, 0, 0);
    __syncthreads();
  }
#pragma unroll
  for (int mt = 0; mt < 4; ++mt)
#pragma unroll
    for (int nt = 0; nt < 4; ++nt)
#pragma unroll
      for (int rr = 0; rr < 4; ++rr) {
        int grow = bm * 128 + wm + mt * 16 + quad * 4 + rr;
        int gcol = bn * 128 + wn + nt * 16 + m16;
        float v = acc[mt][nt][rr];
        if (bias) v += bias[gcol];
        if constexpr (std::is_same<TC, float>::value)
          C[(long)grow * ldc + gcol] = v;
        else
          C[(long)grow * ldc + gcol] = __float2half(v);
      }
}

// ---------------------------------------------------------------------------
// GRU recurrence, register-routed exchange, ONE barrier per step.
// WG (c = blk>>6, b = blk&63): batch b, h-chunk c.
// Wave w consumes only h-chunk s = w>>1 for its dot slice, so each wave polls
// its own chunk's packets directly (lane <-> h-pair 1:1), drops them in a
// per-chunk LDS strip (same-wave lgkm ordering; paired wave writes identical
// values -> benign), and dots immediately. No B2. part[] is parity
// double-buffered; the publish-implies-consumed induction across WGs makes
// two-step reuse safe with the single barrier.
// wave0: reduce + gates + publish packets {h2,tag} + out store + xg prefetch.
//
// ROUND-2 CHANGE: __launch_bounds__(512, 1) — 1 block/CU, 2 waves/SIMD,
// 256-VGPR cap — so the w[192] weight array is truly register-resident
// (old (512,2) build capped at 128 regs -> compiler sank the weight loads
// into the step loop: 192 L2 loads/thread/step, ~50 TB/s L2 demand, the
// real per-step bottleneck). The memory-clobber asm after the preload
// forbids rematerializing those loads inside the loop. 256 WGs now spread
// 1-per-CU across all 256 CUs.
// ---------------------------------------------------------------------------
__global__ __launch_bounds__(512, 1) void gru_rec(
    const uint32_t* __restrict__ wpack, const uint32_t* __restrict__ xgd,
    const float* __restrict__ bhh, uint32_t* __restrict__ hstate,
    uint32_t* __restrict__ outw, uint64_t* __restrict__ pkts,
    float* __restrict__ hid_out,
    int t0, int Tc, int outT, int outT0, int last) {
  const int tid = threadIdx.x;
  const int wave = tid >> 6, lane = tid & 63;
  const int s = tid >> 7;  // k-slice / consumed h-chunk (= wave>>1)
  const int b = blockIdx.x & 63;
  const int c = blockIdx.x >> 6;

  __shared__ uint32_t hbw[4][64];     // per-chunk h strips (fp16x2)
  __shared__ float part[2][3][512];   // parity-double-buffered partials

  uint32_t w[192];
  {
    const uint32_t* wp = wpack + (size_t)(c * 4 + s) * 24576 + (tid & 127);
#pragma unroll
    for (int i = 0; i < 192; ++i) w[i] = wp[(size_t)i * 128];
  }
  // Pin w[] in registers: loads may not be rematerialized (re-issued) past a
  // memory clobber, so the compiler must keep the 192 values live.
  __asm__ volatile("" ::: "memory");

  // wave0 persistent state: running h (2 per lane), n-bias, prefetched xg
  float hold0 = 0.f, hold1 = 0.f, bn0 = 0.f, bn1 = 0.f;
  uint32_t xrw = 0, xzw = 0, xnw = 0;
  if (wave == 0) {
    uint32_t hv = hstate[b * 256 + c * 64 + lane];
    __half2 hh = __builtin_bit_cast(__half2, hv);
    hold0 = __half2float(hh.x);
    hold1 = __half2float(hh.y);
    bn0 = bhh[1024 + c * 128 + 2 * lane];
    bn1 = bhh[1024 + c * 128 + 2 * lane + 1];
    size_t base = ((size_t)b * Tc) * 768 + c * 64 + lane;
    xrw = xgd[base];
    xzw = xgd[base + 256];
    xnw = xgd[base + 512];
  }

  for (int tt = 0; tt < Tc; ++tt) {
    const int t = t0 + tt;
    // ---- acquire the h-chunk this wave's dot slice needs ----
    uint32_t hp;
    if (tt == 0) {
      hp = hstate[b * 256 + s * 64 + lane];  // seeded by prev dispatch
    } else {
      const uint64_t* pp = &pkts[(((size_t)(t & 1)) * 64 + b) * 256 + s * 64 + lane];
      uint64_t v;
      do {
        v = __hip_atomic_load(pp, __ATOMIC_RELAXED, __HIP_MEMORY_SCOPE_AGENT);
      } while ((uint32_t)(v >> 32) != (uint32_t)t);
      hp = (uint32_t)v;
    }
    hbw[s][lane] = hp;  // same-wave lgkm ordering; pair-wave writes same value
    // ---- dots over own k-slice ----
    float ar = 0.f, az = 0.f, an = 0.f;
#pragma unroll
    for (int k4 = 0; k4 < 16; ++k4) {
      uint4 u4 = *((const uint4*)&hbw[s][0] + k4);
      ar = fdot2f(w[(k4 * 4 + 0) * 3 + 0], u4.x, ar);
      az = fdot2f(w[(k4 * 4 + 0) * 3 + 1], u4.x, az);
      an = fdot2f(w[(k4 * 4 + 0) * 3 + 2], u4.x, an);
      ar = fdot2f(w[(k4 * 4 + 1) * 3 + 0], u4.y, ar);
      az = fdot2f(w[(k4 * 4 + 1) * 3 + 1], u4.y, az);
      an = fdot2f(w[(k4 * 4 + 1) * 3 + 2], u4.y, an);
      ar = fdot2f(w[(k4 * 4 + 2) * 3 + 0], u4.z, ar);
      az = fdot2f(w[(k4 * 4 + 2) * 3 + 1], u4.z, az);
      an = fdot2f(w[(k4 * 4 + 2) * 3 + 2], u4.z, an);
      ar = fdot2f(w[(k4 * 4 + 3) * 3 + 0], u4.w, ar);
      az = fdot2f(w[(k4 * 4 + 3) * 3 + 1], u4.w, az);
      an = fdot2f(w[(k4 * 4 + 3) * 3 + 2], u4.w, an);
    }
    const int ps = t & 1;
    part[ps][0][tid] = ar;
    part[ps][1][tid] = az;
    part[ps][2][tid] = an;
    BARX();  // THE one barrier: partials slot ps complete

    if (wave == 0) {
      float hr0 = 0.f, hz0 = 0.f, hn0 = 0.f, hr1 = 0.f, hz1 = 0.f, hn1 = 0.f;
#pragma unroll
      for (int ss = 0; ss < 4; ++ss) {
        float2 vr = *(const float2*)&part[ps][0][ss * 128 + 2 * lane];
        float2 vz = *(const float2*)&part[ps][1][ss * 128 + 2 * lane];
        float2 vn = *(const float2*)&part[ps][2][ss * 128 + 2 * lane];
        hr0 += vr.x; hr1 += vr.y;
        hz0 += vz.x; hz1 += vz.y;
        hn0 += vn.x; hn1 += vn.y;
      }
      __half2 xr = __builtin_bit_cast(__half2, xrw);
      __half2 xz = __builtin_bit_cast(__half2, xzw);
      __half2 xn = __builtin_bit_cast(__half2, xnw);
      float r0 = sigmoid_f(__half2float(xr.x) + hr0);
      float r1 = sigmoid_f(__half2float(xr.y) + hr1);
      float z0 = sigmoid_f(__half2float(xz.x) + hz0);
      float z1 = sigmoid_f(__half2float(xz.y) + hz1);
      float n0 = tanh_f(__half2float(xn.x) + r0 * (hn0 + bn0));
      float n1 = tanh_f(__half2float(xn.y) + r1 * (hn1 + bn1));
      float h0 = (1.f - z0) * n0 + z0 * hold0;
      float h1 = (1.f - z1) * n1 + z1 * hold1;
      hold0 = h0;
      hold1 = h1;
      uint32_t hd = pack_h2(h0, h1);
      // publish: ONE 8B packet {data, tag}; no drain/fence needed
      uint64_t pk = (uint64_t)hd | ((uint64_t)(uint32_t)(t + 1) << 32);
      __hip_atomic_store(&pkts[(((size_t)((t + 1) & 1)) * 64 + b) * 256 + c * 64 + lane],
                         pk, __ATOMIC_RELAXED, __HIP_MEMORY_SCOPE_AGENT);
      // fire-and-forget out store (bf16 pair)
      outw[((size_t)b * outT + outT0 + tt) * 256 + c * 64 + lane] = pack_bf2(h0, h1);
      // prefetch next step's xg (consumed at next gates; ~full step to cover)
      if (tt + 1 < Tc) {
        size_t base = ((size_t)b * Tc + tt + 1) * 768 + c * 64 + lane;
        xrw = xgd[base];
        xzw = xgd[base + 256];
        xnw = xgd[base + 512];
      }
    }
  }

  if (wave == 0) {
    hstate[b * 256 + c * 64 + lane] = pack_h2(hold0, hold1);
    if (last) {
      float2 hv = make_float2(hold0, hold1);
      *(float2*)&hid_out[b * 512 + c * 128 + 2 * lane] = hv;
    }
  }
}

// ---------------------------------------------------------------------------
extern "C" void kernel_launch(void* const* d_in, const int* in_sizes, int n_in,
                              void* d_out, int out_size, void* d_ws, size_t ws_size,
                              hipStream_t stream) {
  const float* x = (const float*)d_in[0];
  const float* W_ih0 = (const float*)d_in[1];
  const float* W_hh0 = (const float*)d_in[2];
  const float* b_ih0 = (const float*)d_in[3];
  const float* b_hh0 = (const float*)d_in[4];
  const float* W_ih1 = (const float*)d_in[5];
  const float* W_hh1 = (const float*)d_in[6];
  const float* b_ih1 = (const float*)d_in[7];
  const float* b_hh1 = (const float*)d_in[8];
  const float* fc_w = (const float*)d_in[9];
  const float* fc_b = (const float*)d_in[10];
  float* out = (float*)d_out;

  char* p = (char*)d_ws;
  size_t off = 0;
  auto alloc = [&](size_t bytes) -> void* {
    void* r = p + off;
    off = (off + bytes + 255) & ~(size_t)255;
    return r;
  };
  uint32_t* wpack = (uint32_t*)alloc((size_t)786432 * 4);
  float* biasv = (float*)alloc((size_t)3072 * 4);
  uint32_t* hstate = (uint32_t*)alloc((size_t)32768 * 4);
  // packets: 2 layers x 2 slots x 64 batch x 4 chunk x 64 lane x u64
  uint64_t* pkts = (uint64_t*)alloc((size_t)2 * 2 * 64 * 4 * 64 * 8);
  __hip_bfloat16* out1 = (__hip_bfloat16*)alloc((size_t)B_ * T_ * H_ * 2);

  int Tc = 1024;
  while (Tc > 64) {
    size_t need = (size_t)B_ * Tc * H_ * 2 + (size_t)B_ * Tc * G3_ * 2 + 1024;
    if (off + need <= ws_size) break;
    Tc >>= 1;
  }
  __hip_bfloat16* out0c = (__hip_bfloat16*)alloc((size_t)B_ * Tc * H_ * 2);
  __half* xg = (__half*)alloc((size_t)B_ * Tc * G3_ * 2);
  int tcs = __builtin_ctz(Tc);

  init_kernel<<<3212, 256, 0, stream>>>(W_hh0, W_hh1, b_ih0, b_hh0, b_ih1, b_hh1,
                                        wpack, biasv, hstate);

  for (int t0 = 0; t0 < 1024; t0 += Tc) {
    const int M = B_ * Tc;
    const int last = (t0 + Tc) == 1024;
    // ---- layer 0 ----
    {
      dim3 gg(M / 128, G3_ / 128);
      gemm_bt<float, __half><<<gg, 256, 0, stream>>>(x, W_ih0, biasv, xg, I_, I_,
                                                     G3_, tcs, t0, 1024);
      gru_rec<<<256, 512, 0, stream>>>(wpack, (const uint32_t*)xg, b_hh0, hstate,
                                       (uint32_t*)out0c, pkts,
                                       out + 16777216, t0, Tc, Tc, 0, last);
    }
    // ---- layer 1 ----
    {
      dim3 gg(M / 128, G3_ / 128);
      gemm_bt<__hip_bfloat16, __half><<<gg, 256, 0, stream>>>(
          out0c, W_ih1, biasv + 1536, xg, H_, H_, G3_, tcs, 0, Tc);
      gru_rec<<<256, 512, 0, stream>>>(wpack + 393216, (const uint32_t*)xg, b_hh1,
                                       hstate + 16384, (uint32_t*)out1,
                                       pkts + 32768,
                                       out + 16777216 + 32768, t0, Tc, 1024, t0, last);
    }
  }
  // FC: [65536,512] x fc_w[256,512]^T + fc_b -> d_out fp32
  dim3 gf(65536 / 128, O_ / 128);
  gemm_bt<__hip_bfloat16, float><<<gf, 256, 0, stream>>>(out1, fc_w, fc_b, out,
                                                         H_, H_, O_, 10, 0, 1024);
}